// Round 8
// baseline (113.194 us; speedup 1.0000x reference)
//
#include <hip/hip_runtime.h>

#define BATCH 8192
#define NUM_SV 8192
#define DIM 256
#define GAMMA 0.1f
#define LOG2E 1.4426950408889634f
// sqrt(2*GAMMA*LOG2E) : pre-scale so MFMA acc == log2-exponent contribution
#define ALPHA 0.53715827f

#define SCHUNK 8              // s-blocks (each block sweeps 1024 sv cols)
#define NST 8                 // s-tiles of 128 per block
#define NKT 4                 // K-tiles of 64
#define BTILE_F16 8192        // B K-tile: 128 cols x 64 k = 16KB

typedef _Float16 f16;
typedef __attribute__((ext_vector_type(8))) _Float16 f16x8;
typedef __attribute__((ext_vector_type(16))) float f32x16;

__device__ __forceinline__ void gload_lds16(const f16* g, f16* l) {
  __builtin_amdgcn_global_load_lds((const __attribute__((address_space(1))) void*)g,
                                   (__attribute__((address_space(3))) void*)l, 16, 0, 0);
}

// ---------------- pre-pass: scaled fp16 copies + norms + dcp ----------------
// x16: plain row-major [row][256] (A is consumed straight into registers).
// sv16: per (128-col tile, 64-k tile) 16KB block laid out
//   [ks=4][kch=2][col=128][8 f16]  so staging is byte-linear and fragment
//   ds_read_b128 (lane lr -> col, lh -> kch) is conflict-free.
__global__ __launch_bounds__(256)
void svm_prep(const float* __restrict__ x, const float* __restrict__ sv,
              const float* __restrict__ dual,
              f16* __restrict__ x16, f16* __restrict__ sv16,
              float* __restrict__ xg, float* __restrict__ dcp) {
  const int id = blockIdx.x * 256 + threadIdx.x;
  const bool isx = id < (BATCH * DIM / 8);
  const int lid = isx ? id : id - (BATCH * DIM / 8);
  const int row = lid >> 5;
  const int k0  = (lid & 31) << 3;

  const float* src = (isx ? x : sv) + (size_t)row * DIM + k0;
  float4 u = *(const float4*)(src);
  float4 v = *(const float4*)(src + 4);

  float sq = u.x*u.x + u.y*u.y + u.z*u.z + u.w*u.w
           + v.x*v.x + v.y*v.y + v.z*v.z + v.w*v.w;
  #pragma unroll
  for (int m = 1; m <= 16; m <<= 1) sq += __shfl_xor(sq, m, 32);
  if ((lid & 31) == 0) {
    float g = -(GAMMA * LOG2E) * sq;
    if (isx) xg[row] = g;
    else     dcp[row] = dual[row] * __builtin_amdgcn_exp2f(g);
  }

  f16x8 h;
  h[0] = (f16)(ALPHA * u.x); h[1] = (f16)(ALPHA * u.y);
  h[2] = (f16)(ALPHA * u.z); h[3] = (f16)(ALPHA * u.w);
  h[4] = (f16)(ALPHA * v.x); h[5] = (f16)(ALPHA * v.y);
  h[6] = (f16)(ALPHA * v.z); h[7] = (f16)(ALPHA * v.w);

  if (isx) {
    *(f16x8*)&x16[(size_t)row * DIM + k0] = h;
  } else {
    const int tile = row >> 7;          // 128-col sv tile
    const int col  = row & 127;
    const int kt   = k0 >> 6;
    const int ks   = (k0 >> 4) & 3;
    const int kch  = (k0 >> 3) & 1;
    f16* dst = sv16 + (size_t)(tile * NKT + kt) * BTILE_F16
             + ((ks * 2 + kch) * 128 + col) * 8;
    *(f16x8*)dst = h;
  }
}

// ---------------- main fused MFMA kernel: A-in-registers, B via LDS dbuf ----
// 256 threads = 4 waves (wb=0..1: 64-row strip, wn=0..1: 64-col strip);
// wave tile 64x64 as 2x2 of mfma_f32_32x32x16_f16. Each wave holds its
// full A panel (64 rows x 256 k) in 128 VGPRs, loaded once; only B is
// staged (16KB per K-tile, double-buffered). 2 blocks/CU co-resident.
__global__ __launch_bounds__(256, 2)
void svm_main(const f16* __restrict__ x16, const f16* __restrict__ sv16,
              const float* __restrict__ dcp, float* __restrict__ partial) {
  __shared__ f16 bbuf[2][BTILE_F16];   // 32KB
  __shared__ float dcpl[NST * 128];    // 4KB
  __shared__ float red[2][128];

  const int tid = threadIdx.x;
  const int w   = tid >> 6;
  const int l   = tid & 63;
  const int lr  = l & 31;
  const int lh  = l >> 5;
  const int wb  = w >> 1;        // 0..1 : 64-row strip
  const int wn  = w & 1;         // 0..1 : 64-col strip

  // bijective XCD remap: each XCD gets a 16(bt) x 2(sch) rectangle
  // -> working set 16*64KB(x) + 2*512KB(sv) = 3MB < 4MB L2.
  const int bid = blockIdx.x;
  const int q   = bid & 7;
  const int idx = bid >> 3;            // 0..63
  const int bt  = (q & 3) * 16 + (idx & 15);    // 0..63 (128-row tile)
  const int sch = (q >> 2) * 4 + (idx >> 4);    // 0..7

  // dcp factors for this block's 1024 sv cols -> LDS
  *(float4*)&dcpl[tid * 4] = *(const float4*)&dcp[sch * 1024 + tid * 4];

  // ---- A panel -> registers (once): af[m][kk], kk = global 16-k slice ----
  f16x8 af[2][16];
  {
    const f16* xb = x16 + (size_t)(bt * 128 + wb * 64 + lr) * DIM + lh * 8;
    #pragma unroll
    for (int m = 0; m < 2; ++m)
      #pragma unroll
      for (int kk = 0; kk < 16; ++kk)
        af[m][kk] = *(const f16x8*)&xb[m * 32 * DIM + kk * 16];
  }

  // stage B K-tile (16KB): 4 x gload_lds16 per thread, byte-linear
  auto stageB = [&](int bb, int stile, int kt) {
    const f16* src = sv16 + (size_t)(stile * NKT + kt) * BTILE_F16 + tid * 8;
    f16* dst = &bbuf[bb][tid * 8];
    #pragma unroll
    for (int i = 0; i < 4; ++i)
      gload_lds16(src + i * 2048, dst + i * 2048);
  };

  float ctr[2][16];
  #pragma unroll
  for (int m = 0; m < 2; ++m)
    #pragma unroll
    for (int r = 0; r < 16; ++r) ctr[m][r] = 0.f;

  stageB(0, sch * NST, 0);

  #pragma unroll 1
  for (int st = 0; st < NST; ++st) {
    f32x16 acc[2][2];
    #pragma unroll
    for (int m = 0; m < 2; ++m)
      #pragma unroll
      for (int n = 0; n < 2; ++n)
        #pragma unroll
        for (int r = 0; r < 16; ++r) acc[m][n][r] = 0.f;

    #pragma unroll 1
    for (int kt = 0; kt < NKT; ++kt) {
      const int t = st * NKT + kt;
      __syncthreads();   // bbuf[t&1] staged; previous readers done

      if (t + 1 < NST * NKT) {
        const int t1 = t + 1;
        stageB(t1 & 1, sch * NST + (t1 >> 2), t1 & 3);
      }

      const f16* buf = bbuf[t & 1];
      #pragma unroll
      for (int ks = 0; ks < 4; ++ks) {
        const int ko = (ks * 2 + lh) * 128;
        f16x8 b0 = *(const f16x8*)&buf[(ko + wn * 64 +  0 + lr) * 8];
        f16x8 b1 = *(const f16x8*)&buf[(ko + wn * 64 + 32 + lr) * 8];
        const int kk = kt * 4 + ks;
        acc[0][0] = __builtin_amdgcn_mfma_f32_32x32x16_f16(af[0][kk], b0, acc[0][0], 0, 0, 0);
        acc[0][1] = __builtin_amdgcn_mfma_f32_32x32x16_f16(af[0][kk], b1, acc[0][1], 0, 0, 0);
        acc[1][0] = __builtin_amdgcn_mfma_f32_32x32x16_f16(af[1][kk], b0, acc[1][0], 0, 0, 0);
        acc[1][1] = __builtin_amdgcn_mfma_f32_32x32x16_f16(af[1][kk], b1, acc[1][1], 0, 0, 0);
      }
    }

    // ---- fused epilogue for s-tile st (regs + dcpl LDS reads only)
    #pragma unroll
    for (int n = 0; n < 2; ++n) {
      const float dv = dcpl[st * 128 + wn * 64 + n * 32 + lr];
      #pragma unroll
      for (int m = 0; m < 2; ++m)
        #pragma unroll
        for (int r = 0; r < 16; ++r)
          ctr[m][r] = fmaf(__builtin_amdgcn_exp2f(acc[m][n][r]), dv, ctr[m][r]);
    }
  }

  // ---- reduce ctr across the 32 col-lanes sharing each row set
  #pragma unroll
  for (int m = 0; m < 2; ++m)
    #pragma unroll
    for (int r = 0; r < 16; ++r) {
      float v = ctr[m][r];
      v += __shfl_xor(v, 1, 64);
      v += __shfl_xor(v, 2, 64);
      v += __shfl_xor(v, 4, 64);
      v += __shfl_xor(v, 8, 64);
      v += __shfl_xor(v, 16, 64);
      ctr[m][r] = v;
    }

  __syncthreads();
  if (lr == 0) {
    #pragma unroll
    for (int m = 0; m < 2; ++m)
      #pragma unroll
      for (int r = 0; r < 16; ++r) {
        const int rl = wb * 64 + m * 32 + (r & 3) + 8 * (r >> 2) + 4 * lh;
        red[wn][rl] = ctr[m][r];
      }
  }
  __syncthreads();
  if (tid < 128)
    partial[(size_t)sch * BATCH + bt * 128 + tid] = red[0][tid] + red[1][tid];
}

// ---------------- final reduction + x-norm factor ----------------
__global__ __launch_bounds__(256)
void svm_reduce(const float* __restrict__ partial, const float* __restrict__ xg,
                float* __restrict__ out) {
  const int b = blockIdx.x * 256 + threadIdx.x;
  float s = 0.f;
  #pragma unroll
  for (int c = 0; c < SCHUNK; ++c) s += partial[(size_t)c * BATCH + b];
  out[b] = __builtin_amdgcn_exp2f(xg[b]) * s;
}

extern "C" void kernel_launch(void* const* d_in, const int* in_sizes, int n_in,
                              void* d_out, int out_size, void* d_ws, size_t ws_size,
                              hipStream_t stream) {
  const float* x    = (const float*)d_in[0];
  const float* sv   = (const float*)d_in[1];
  const float* dual = (const float*)d_in[2];
  float* out = (float*)d_out;

  f16*   x16     = (f16*)d_ws;                       // 4MB
  f16*   sv16    = x16 + (size_t)BATCH * DIM;        // 4MB
  float* xg      = (float*)(sv16 + (size_t)NUM_SV * DIM);
  float* dcp     = xg + BATCH;
  float* partial = dcp + NUM_SV;                     // SCHUNK * BATCH

  svm_prep<<<(BATCH + NUM_SV) * DIM / 8 / 256, 256, 0, stream>>>(x, sv, dual, x16, sv16, xg, dcp);
  svm_main<<<(BATCH / 128) * SCHUNK, 256, 0, stream>>>(x16, sv16, dcp, partial);
  svm_reduce<<<BATCH / 256, 256, 0, stream>>>(partial, xg, out);
}

// Round 9
// 55.018 us; speedup vs baseline: 2.0574x; 2.0574x over previous
//
#include <hip/hip_runtime.h>

#define BATCH 8192
#define NUM_SV 8192
#define DIM 256
#define GAMMA 0.1f
#define LOG2E 1.4426950408889634f
// sqrt(2*GAMMA*LOG2E) : pre-scale so MFMA acc == log2-exponent contribution
#define ALPHA 0.53715827f

#define SCHUNK 8              // s-blocks (each block sweeps 1024 sv cols)
#define NST 8                 // s-tiles of 128 per block
#define NKT 4                 // K-tiles of 64
#define BTILE_F16 8192        // B K-tile: 128 cols x 64 k = 16KB

typedef _Float16 f16;
typedef __attribute__((ext_vector_type(8))) _Float16 f16x8;
typedef __attribute__((ext_vector_type(16))) float f32x16;

__device__ __forceinline__ void gload_lds16(const f16* g, f16* l) {
  __builtin_amdgcn_global_load_lds((const __attribute__((address_space(1))) void*)g,
                                   (__attribute__((address_space(3))) void*)l, 16, 0, 0);
}

// ---------------- pre-pass: scaled fp16 copies + norms + dcp ----------------
// x16: plain row-major [row][256]. sv16: per (128-col tile, 64-k tile) 16KB
// block [ks=4][kch=2][col=128][8 f16] -> staging byte-linear, fragment
// ds_read_b128 conflict-free.
__global__ __launch_bounds__(256)
void svm_prep(const float* __restrict__ x, const float* __restrict__ sv,
              const float* __restrict__ dual,
              f16* __restrict__ x16, f16* __restrict__ sv16,
              float* __restrict__ xg, float* __restrict__ dcp) {
  const int id = blockIdx.x * 256 + threadIdx.x;
  const bool isx = id < (BATCH * DIM / 8);
  const int lid = isx ? id : id - (BATCH * DIM / 8);
  const int row = lid >> 5;
  const int k0  = (lid & 31) << 3;

  const float* src = (isx ? x : sv) + (size_t)row * DIM + k0;
  float4 u = *(const float4*)(src);
  float4 v = *(const float4*)(src + 4);

  float sq = u.x*u.x + u.y*u.y + u.z*u.z + u.w*u.w
           + v.x*v.x + v.y*v.y + v.z*v.z + v.w*v.w;
  #pragma unroll
  for (int m = 1; m <= 16; m <<= 1) sq += __shfl_xor(sq, m, 32);
  if ((lid & 31) == 0) {
    float g = -(GAMMA * LOG2E) * sq;
    if (isx) xg[row] = g;
    else     dcp[row] = dual[row] * __builtin_amdgcn_exp2f(g);
  }

  f16x8 h;
  h[0] = (f16)(ALPHA * u.x); h[1] = (f16)(ALPHA * u.y);
  h[2] = (f16)(ALPHA * u.z); h[3] = (f16)(ALPHA * u.w);
  h[4] = (f16)(ALPHA * v.x); h[5] = (f16)(ALPHA * v.y);
  h[6] = (f16)(ALPHA * v.z); h[7] = (f16)(ALPHA * v.w);

  if (isx) {
    *(f16x8*)&x16[(size_t)row * DIM + k0] = h;
  } else {
    const int tile = row >> 7;
    const int col  = row & 127;
    const int kt   = k0 >> 6;
    const int ks   = (k0 >> 4) & 3;
    const int kch  = (k0 >> 3) & 1;
    f16* dst = sv16 + (size_t)(tile * NKT + kt) * BTILE_F16
             + ((ks * 2 + kch) * 128 + col) * 8;
    *(f16x8*)dst = h;
  }
}

// ---------------- main fused MFMA kernel: A-in-registers, B via LDS dbuf ----
// 256 threads = 4 waves (wb x wn); wave tile 64x64 as 2x2 of
// mfma_f32_32x32x16_f16. A panel (64x256 f16 = 128 VGPR/wave) loaded once,
// ALL indexing compile-time (kt loop fully unrolled — rule #20). Only B
// staged in LDS (dbuf 2x16KB). 2 blocks/CU.
__global__ __launch_bounds__(256, 2)
void svm_main(const f16* __restrict__ x16, const f16* __restrict__ sv16,
              const float* __restrict__ dcp, float* __restrict__ partial) {
  __shared__ f16 bbuf[2][BTILE_F16];   // 32KB
  __shared__ float dcpl[NST * 128];    // 4KB
  __shared__ float red[2][128];

  const int tid = threadIdx.x;
  const int w   = tid >> 6;
  const int l   = tid & 63;
  const int lr  = l & 31;
  const int lh  = l >> 5;
  const int wb  = w >> 1;
  const int wn  = w & 1;

  // bijective XCD remap: each XCD gets a 16(bt) x 2(sch) rectangle
  const int bid = blockIdx.x;
  const int q   = bid & 7;
  const int idx = bid >> 3;
  const int bt  = (q & 3) * 16 + (idx & 15);    // 0..63
  const int sch = (q >> 2) * 4 + (idx >> 4);    // 0..7

  *(float4*)&dcpl[tid * 4] = *(const float4*)&dcp[sch * 1024 + tid * 4];

  // ---- A panel -> registers (once); static indices only ----
  f16x8 af[2][16];
  {
    const f16* xb = x16 + (size_t)(bt * 128 + wb * 64 + lr) * DIM + lh * 8;
    #pragma unroll
    for (int m = 0; m < 2; ++m)
      #pragma unroll
      for (int kk = 0; kk < 16; ++kk)
        af[m][kk] = *(const f16x8*)&xb[m * 32 * DIM + kk * 16];
  }

  auto stageB = [&](int bb, int stile, int kt) {
    const f16* src = sv16 + (size_t)(stile * NKT + kt) * BTILE_F16 + tid * 8;
    f16* dst = &bbuf[bb][tid * 8];
    #pragma unroll
    for (int i = 0; i < 4; ++i)
      gload_lds16(src + i * 2048, dst + i * 2048);
  };

  float ctr[2][16];
  #pragma unroll
  for (int m = 0; m < 2; ++m)
    #pragma unroll
    for (int r = 0; r < 16; ++r) ctr[m][r] = 0.f;

  stageB(0, sch * NST, 0);

  #pragma unroll 1
  for (int st = 0; st < NST; ++st) {
    f32x16 acc[2][2];
    #pragma unroll
    for (int m = 0; m < 2; ++m)
      #pragma unroll
      for (int n = 0; n < 2; ++n)
        #pragma unroll
        for (int r = 0; r < 16; ++r) acc[m][n][r] = 0.f;

    #pragma unroll              // kt FULLY unrolled: af index + buffer parity static
    for (int kt = 0; kt < NKT; ++kt) {
      __syncthreads();          // bbuf[kt&1] staged; previous readers done

      // prefetch next K-tile (parity (kt+1)&1, compile-time)
      if (kt < NKT - 1) {
        stageB((kt + 1) & 1, sch * NST + st, kt + 1);
      } else if (st < NST - 1) {
        stageB((kt + 1) & 1, sch * NST + st + 1, 0);
      }

      const f16* buf = bbuf[kt & 1];
      #pragma unroll
      for (int ks = 0; ks < 4; ++ks) {
        const int ko = (ks * 2 + lh) * 128;
        f16x8 b0 = *(const f16x8*)&buf[(ko + wn * 64 +  0 + lr) * 8];
        f16x8 b1 = *(const f16x8*)&buf[(ko + wn * 64 + 32 + lr) * 8];
        acc[0][0] = __builtin_amdgcn_mfma_f32_32x32x16_f16(af[0][kt * 4 + ks], b0, acc[0][0], 0, 0, 0);
        acc[0][1] = __builtin_amdgcn_mfma_f32_32x32x16_f16(af[0][kt * 4 + ks], b1, acc[0][1], 0, 0, 0);
        acc[1][0] = __builtin_amdgcn_mfma_f32_32x32x16_f16(af[1][kt * 4 + ks], b0, acc[1][0], 0, 0, 0);
        acc[1][1] = __builtin_amdgcn_mfma_f32_32x32x16_f16(af[1][kt * 4 + ks], b1, acc[1][1], 0, 0, 0);
      }
    }

    // ---- fused epilogue for s-tile st (regs + dcpl LDS reads only)
    #pragma unroll
    for (int n = 0; n < 2; ++n) {
      const float dv = dcpl[st * 128 + wn * 64 + n * 32 + lr];
      #pragma unroll
      for (int m = 0; m < 2; ++m)
        #pragma unroll
        for (int r = 0; r < 16; ++r)
          ctr[m][r] = fmaf(__builtin_amdgcn_exp2f(acc[m][n][r]), dv, ctr[m][r]);
    }
  }

  // ---- reduce ctr across the 32 col-lanes sharing each row set
  #pragma unroll
  for (int m = 0; m < 2; ++m)
    #pragma unroll
    for (int r = 0; r < 16; ++r) {
      float v = ctr[m][r];
      v += __shfl_xor(v, 1, 64);
      v += __shfl_xor(v, 2, 64);
      v += __shfl_xor(v, 4, 64);
      v += __shfl_xor(v, 8, 64);
      v += __shfl_xor(v, 16, 64);
      ctr[m][r] = v;
    }

  __syncthreads();
  if (lr == 0) {
    #pragma unroll
    for (int m = 0; m < 2; ++m)
      #pragma unroll
      for (int r = 0; r < 16; ++r) {
        const int rl = wb * 64 + m * 32 + (r & 3) + 8 * (r >> 2) + 4 * lh;
        red[wn][rl] = ctr[m][r];
      }
  }
  __syncthreads();
  if (tid < 128)
    partial[(size_t)sch * BATCH + bt * 128 + tid] = red[0][tid] + red[1][tid];
}

// ---------------- final reduction + x-norm factor ----------------
__global__ __launch_bounds__(256)
void svm_reduce(const float* __restrict__ partial, const float* __restrict__ xg,
                float* __restrict__ out) {
  const int b = blockIdx.x * 256 + threadIdx.x;
  float s = 0.f;
  #pragma unroll
  for (int c = 0; c < SCHUNK; ++c) s += partial[(size_t)c * BATCH + b];
  out[b] = __builtin_amdgcn_exp2f(xg[b]) * s;
}

extern "C" void kernel_launch(void* const* d_in, const int* in_sizes, int n_in,
                              void* d_out, int out_size, void* d_ws, size_t ws_size,
                              hipStream_t stream) {
  const float* x    = (const float*)d_in[0];
  const float* sv   = (const float*)d_in[1];
  const float* dual = (const float*)d_in[2];
  float* out = (float*)d_out;

  f16*   x16     = (f16*)d_ws;                       // 4MB
  f16*   sv16    = x16 + (size_t)BATCH * DIM;        // 4MB
  float* xg      = (float*)(sv16 + (size_t)NUM_SV * DIM);
  float* dcp     = xg + BATCH;
  float* partial = dcp + NUM_SV;                     // SCHUNK * BATCH

  svm_prep<<<(BATCH + NUM_SV) * DIM / 8 / 256, 256, 0, stream>>>(x, sv, dual, x16, sv16, xg, dcp);
  svm_main<<<(BATCH / 128) * SCHUNK, 256, 0, stream>>>(x16, sv16, dcp, partial);
  svm_reduce<<<BATCH / 256, 256, 0, stream>>>(partial, xg, out);
}